// Round 4
// baseline (267.087 us; speedup 1.0000x reference)
//
#include <hip/hip_runtime.h>
#include <hip/hip_bf16.h>
#include <cstddef>

// Problem: BS=8, NE=128, ENT=768, REL=768, RANK=256, OUT=256
// rows M = 8*128*128 = 131072; rel row-major [b][i][j][768]
// ws: l1 [1024*256 f32] | l2 [1024*256 f32] | W3g [196608 bf16 frag] | Weg [65536 bf16 frag]
// Fragment-major B: flat = ((kq*256 + n)*4 + g)*8 + e  (kq=k/32, g=(k/8)%4, e=k%7)
// -> one wave B-fragment load = contiguous 1 KB global_load_dwordx4.

typedef __attribute__((ext_vector_type(8))) short short8;
typedef __attribute__((ext_vector_type(4))) float f32x4;

__device__ __forceinline__ unsigned short f2bf(float x) {
  union { float f; unsigned u; } v; v.f = x;
  unsigned r = (v.u + 0x7FFFu + ((v.u >> 16) & 1u)) >> 16;  // RNE
  return (unsigned short)r;
}
__device__ __forceinline__ unsigned short cvt1(float x) {
  return __bfloat16_as_ushort(__float2bfloat16(x));  // pairs to v_cvt_pk_bf16_f32
}
__device__ __forceinline__ f32x4 mfma16(short8 a, short8 b, f32x4 c) {
  return __builtin_amdgcn_mfma_f32_16x16x32_bf16(a, b, c, 0, 0, 0);
}
__device__ __forceinline__ void gload_lds16(const float* g, float* l) {
  __builtin_amdgcn_global_load_lds((__attribute__((address_space(1))) void*)(g),
                                   (__attribute__((address_space(3))) void*)(l), 16, 0, 0);
}

// read 8 f32 from swizzled LDS tile, convert to bf16 frag
__device__ __forceinline__ short8 frag_cvt(const float* p) {
  f32x4 lo = *(const f32x4*)p;
  f32x4 hi = *(const f32x4*)(p + 4);
  short8 s;
  s[0] = (short)cvt1(lo[0]); s[1] = (short)cvt1(lo[1]);
  s[2] = (short)cvt1(lo[2]); s[3] = (short)cvt1(lo[3]);
  s[4] = (short)cvt1(hi[0]); s[5] = (short)cvt1(hi[1]);
  s[6] = (short)cvt1(hi[2]); s[7] = (short)cvt1(hi[3]);
  return s;
}

// ---------------- prep (single launch, grid 1280):
// blocks 0..255   : l{1,2} = x @ W^T + bias   (8 rows/block)
// blocks 256..1279: W3/We -> bf16 fragment-major
__global__ __launch_bounds__(256) void prep_all(
    const float* __restrict__ sub, const float* __restrict__ obj,
    const float* __restrict__ W1, const float* __restrict__ b1,
    const float* __restrict__ W2, const float* __restrict__ b2,
    const float* __restrict__ W3, const float* __restrict__ We,
    float* __restrict__ l1p, float* __restrict__ l2p,
    unsigned short* __restrict__ W3g, unsigned short* __restrict__ Weg) {
  const int tid = threadIdx.x;
  if (blockIdx.x >= 256) {
    int idx = (blockIdx.x - 256) * 256 + tid;  // 0..262143
    if (idx < 196608) {
      int n = idx / 768, k = idx % 768;
      int f = ((k >> 5) * 256 + n) * 32 + ((k >> 3) & 3) * 8 + (k & 7);
      W3g[f] = f2bf(W3[idx]);
    }
    int j = idx - 196608;
    if (j >= 0 && j < 65536) {
      int n = j / 256, k = j % 256;
      int f = ((k >> 5) * 256 + n) * 32 + ((k >> 3) & 3) * 8 + (k & 7);
      Weg[f] = f2bf(We[j]);
    }
    return;
  }
  const int half = blockIdx.x >> 7;  // 0: sub, 1: obj
  const float* x = half ? obj : sub;
  const float* W = half ? W2 : W1;
  const float* bias = half ? b2 : b1;
  float* outp = half ? l2p : l1p;

  __shared__ float xs[8][768];
  const int R0 = (blockIdx.x & 127) * 8;
  #pragma unroll
  for (int c = 0; c < 6; ++c) {
    int f4i = c * 256 + tid;
    int row = f4i / 192;
    int c4 = f4i % 192;
    *(float4*)&xs[row][c4 * 4] = *(const float4*)&x[(size_t)(R0 + row) * 768 + c4 * 4];
  }
  __syncthreads();
  const int col = tid;
  const float* Wr = W + (size_t)col * 768;
  float a[8] = {0.f, 0.f, 0.f, 0.f, 0.f, 0.f, 0.f, 0.f};
  for (int k4 = 0; k4 < 192; ++k4) {
    float4 wv = *(const float4*)&Wr[k4 * 4];
    #pragma unroll
    for (int r = 0; r < 8; ++r) {
      float4 xv = *(const float4*)&xs[r][k4 * 4];
      a[r] += wv.x * xv.x + wv.y * xv.y + wv.z * xv.z + wv.w * xv.w;
    }
  }
  float bb = bias[col];
  #pragma unroll
  for (int r = 0; r < 8; ++r)
    outp[(size_t)(R0 + r) * 256 + col] = a[r] + bb;
}

// ---------------- fused main kernel ------------------------------------------
__global__ __launch_bounds__(256, 4) void fused_main(
    const float* __restrict__ rel, const float* __restrict__ l1p,
    const float* __restrict__ l2p, const unsigned short* __restrict__ W3g,
    const unsigned short* __restrict__ Weg, const float* __restrict__ b3,
    const float* __restrict__ be, const float* __restrict__ lng,
    const float* __restrict__ lnb, float* __restrict__ out) {
  __shared__ union U {
    float stgf[2][4096];            // 2 x (64 rows x 64 f32), source-swizzled; 32 KB
    unsigned short prod[64][256];   // 32 KB
  } u;
  __shared__ float l1s[256], b3s[256], bes[256], gs[256], bsh[256];
  __shared__ float ps[64][4], pq[64][4], mus[64], rss[64];

  const int tid = threadIdx.x;
  const int wave = tid >> 6;
  const int lane = tid & 63;
  const int g = lane >> 4;
  const int c16 = lane & 15;

  const int R0 = blockIdx.x * 64;
  const int b = R0 >> 14;
  const int rem = R0 & 16383;
  const int i = rem >> 7;
  const int j0 = rem & 127;  // 0 or 64

  const float* relBase = rel + (size_t)((b * 128 + i) * 128 + j0) * 768;

  l1s[tid] = l1p[(b * 128 + i) * 256 + tid];
  b3s[tid] = b3[tid];
  bes[tid] = be[tid];
  gs[tid] = lng[tid];
  bsh[tid] = lnb[tid];

  // ---- staging geometry (T21): linear LDS dest, inverse-swizzled global src.
  // LDS[r][u] (16B units) holds G[r][u ^ ((r&7)<<1)].
  const int lq = lane >> 4;   // row within 4-row chunk
  const int u16 = lane & 15;  // 16B unit within row
  const float* gsrc[4];
  #pragma unroll
  for (int q = 0; q < 4; ++q) {
    int r = (wave * 4 + q) * 4 + lq;
    int ug = u16 ^ ((r & 7) << 1);
    gsrc[q] = relBase + (size_t)r * 768 + ug * 4;
  }

#define ISSUE(BUF, KS)                                                         \
  {                                                                            \
    _Pragma("unroll") for (int q = 0; q < 4; ++q)                              \
        gload_lds16(gsrc[q] + (KS) * 64, &u.stgf[BUF][(wave * 4 + q) * 256]);  \
  }

  f32x4 acc1[4][4] = {};
  short8 regB[8];  // B-fragments of CURRENT tile, [sub*4+fn]

  auto loadB = [&](int ks) {
    #pragma unroll
    for (int sub = 0; sub < 2; ++sub) {
      #pragma unroll
      for (int fn = 0; fn < 4; ++fn) {
        const int n = wave * 64 + fn * 16 + c16;
        regB[sub * 4 + fn] = *(const short8*)&W3g[(((ks * 2 + sub) * 256 + n) * 4 + g) * 8];
      }
    }
  };

  auto compute_tile = [&](int buf) {
    const float* base = &u.stgf[buf][0];
    #pragma unroll
    for (int sub = 0; sub < 2; ++sub) {
      short8 ah[4];
      #pragma unroll
      for (int fm = 0; fm < 4; ++fm) {
        const int r = fm * 16 + c16;
        const int gg = sub * 4 + g;
        ah[fm] = frag_cvt(base + r * 64 + ((gg ^ (r & 7)) << 3));
      }
      #pragma unroll
      for (int fn = 0; fn < 4; ++fn) {
        #pragma unroll
        for (int fm = 0; fm < 4; ++fm)
          acc1[fm][fn] = mfma16(ah[fm], regB[sub * 4 + fn], acc1[fm][fn]);
      }
    }
  };

  __syncthreads();  // l1s etc. visible; nothing in flight yet
  ISSUE(0, 0);
  loadB(0);

  for (int ks = 0; ks < 12; ++ks) {
    const int buf = ks & 1;
    if (ks < 11) ISSUE(buf ^ 1, ks + 1);
    // queue: [stage(ks), B(ks), stage(ks+1)] -> drain first two, keep last 4
    if (ks < 11) {
      asm volatile("s_waitcnt vmcnt(4)" ::: "memory");
    } else {
      asm volatile("s_waitcnt vmcnt(0)" ::: "memory");
    }
    __builtin_amdgcn_s_barrier();
    __builtin_amdgcn_sched_barrier(0);
    compute_tile(buf);
    __builtin_amdgcn_sched_barrier(0);
    if (ks < 11) loadB(ks + 1);  // issued BEFORE next iter's ISSUE -> FIFO-clean
    __builtin_amdgcn_sched_barrier(0);
    __builtin_amdgcn_s_barrier();
  }

  // ---- epilogue 1: prod = (l3 + b3) * l1 * l2 -> bf16 swizzled LDS ----
  #pragma unroll
  for (int fm = 0; fm < 4; ++fm) {
    #pragma unroll
    for (int r = 0; r < 4; ++r) {
      const int m = fm * 16 + g * 4 + r;
      const float* l2row = l2p + (size_t)(b * 128 + j0 + m) * 256;
      #pragma unroll
      for (int fn = 0; fn < 4; ++fn) {
        const int col = wave * 64 + fn * 16 + c16;
        float v = (acc1[fm][fn][r] + b3s[col]) * l1s[col] * l2row[col];
        u.prod[m][col ^ ((m & 7) << 3)] = f2bf(v);
      }
    }
  }
  __syncthreads();

  // ---- GEMM2: f = prod @ Web^T (Weg fragment-major) ----
  f32x4 acc2[4][4] = {};
  #pragma unroll
  for (int kk = 0; kk < 8; ++kk) {
    short8 a2[4];
    #pragma unroll
    for (int fm = 0; fm < 4; ++fm) {
      const int m = fm * 16 + c16;
      a2[fm] = *(const short8*)&u.prod[m][(kk * 32 + g * 8) ^ ((m & 7) << 3)];
    }
    #pragma unroll
    for (int fn = 0; fn < 4; ++fn) {
      const int n = wave * 64 + fn * 16 + c16;
      short8 bfr = *(const short8*)&Weg[((kk * 256 + n) * 4 + g) * 8];
      #pragma unroll
      for (int fm = 0; fm < 4; ++fm)
        acc2[fm][fn] = mfma16(a2[fm], bfr, acc2[fm][fn]);
    }
  }

  // ---- LN stats ----
  #pragma unroll
  for (int fm = 0; fm < 4; ++fm) {
    #pragma unroll
    for (int r = 0; r < 4; ++r) {
      float s1 = 0.f, s2 = 0.f;
      #pragma unroll
      for (int fn = 0; fn < 4; ++fn) {
        const int col = wave * 64 + fn * 16 + c16;
        float v = acc2[fm][fn][r] + bes[col];
        s1 += v; s2 += v * v;
      }
      #pragma unroll
      for (int off = 1; off < 16; off <<= 1) {
        s1 += __shfl_xor(s1, off);
        s2 += __shfl_xor(s2, off);
      }
      if (c16 == 0) {
        const int m = fm * 16 + g * 4 + r;
        ps[m][wave] = s1; pq[m][wave] = s2;
      }
    }
  }
  __syncthreads();
  if (tid < 64) {
    float s = ps[tid][0] + ps[tid][1] + ps[tid][2] + ps[tid][3];
    float q = pq[tid][0] + pq[tid][1] + pq[tid][2] + pq[tid][3];
    float mu = s * 0.00390625f;
    float var = q * 0.00390625f - mu * mu;
    mus[tid] = mu;
    rss[tid] = rsqrtf(var + 1e-6f);
  }
  __syncthreads();

  // ---- store ----
  #pragma unroll
  for (int fm = 0; fm < 4; ++fm) {
    #pragma unroll
    for (int r = 0; r < 4; ++r) {
      const int m = fm * 16 + g * 4 + r;
      const float mu = mus[m], rs = rss[m];
      float* orow = out + (size_t)(R0 + m) * 256;
      #pragma unroll
      for (int fn = 0; fn < 4; ++fn) {
        const int col = wave * 64 + fn * 16 + c16;
        float v = acc2[fm][fn][r] + bes[col];
        orow[col] = (v - mu) * rs * gs[col] + bsh[col];
      }
    }
  }
#undef ISSUE
}

extern "C" void kernel_launch(void* const* d_in, const int* in_sizes, int n_in,
                              void* d_out, int out_size, void* d_ws, size_t ws_size,
                              hipStream_t stream) {
  const float* sub = (const float*)d_in[0];
  const float* obj = (const float*)d_in[1];
  const float* rel = (const float*)d_in[2];
  const float* W1 = (const float*)d_in[3];
  const float* b1 = (const float*)d_in[4];
  const float* W2 = (const float*)d_in[5];
  const float* b2 = (const float*)d_in[6];
  const float* W3 = (const float*)d_in[7];
  const float* b3 = (const float*)d_in[8];
  const float* We = (const float*)d_in[9];
  const float* be = (const float*)d_in[10];
  const float* lng = (const float*)d_in[11];
  const float* lnb = (const float*)d_in[12];
  float* out = (float*)d_out;

  float* ws = (float*)d_ws;
  float* l1p = ws;
  float* l2p = ws + 262144;
  unsigned short* W3g = (unsigned short*)(ws + 524288);
  unsigned short* Weg = W3g + 196608;

  prep_all<<<1280, 256, 0, stream>>>(sub, obj, W1, b1, W2, b2, W3, We, l1p, l2p, W3g, Weg);
  fused_main<<<2048, 256, 0, stream>>>(rel, l1p, l2p, W3g, Weg, b3, be, lng, lnb, out);
}